// Round 1
// baseline (3140.370 us; speedup 1.0000x reference)
//
#include <hip/hip_runtime.h>
#include <hip/hip_bf16.h>
#include <math.h>
#include <stdint.h>

using bf16 = __hip_bfloat16;
typedef __attribute__((ext_vector_type(8))) short short8;
typedef __attribute__((ext_vector_type(4))) float f32x4;

#define LOG2E 1.44269504088896340736f

enum { EPI_BF16 = 0, EPI_GVF = 1, EPI_RES = 2, EPI_F32 = 3 };

__device__ __forceinline__ float bf2f(bf16 v) { return __bfloat162float(v); }
__device__ __forceinline__ bf16 f2bf(float v) { return __float2bfloat16(v); }
__device__ __forceinline__ unsigned short f2bfraw(float f) {
  bf16 h = __float2bfloat16(f);
  unsigned short u;
  __builtin_memcpy(&u, &h, 2);
  return u;
}

// LDS swizzles (element index into bf16 tile). Derived for 2-way (free) bank
// aliasing on ds_read_b128 fragment reads:
//  - 32-col (64B-row) tiles: slot ^= (row>>1)&3  (bank quad period is 2 rows)
//  - 64-col (128B-row) tiles: slot ^= row&7
__device__ __forceinline__ int swz64(int row, int col) {
  return row * 32 + ((((col >> 3) ^ ((row >> 1) & 3)) << 3) | (col & 7));
}
__device__ __forceinline__ int swz128(int row, int col) {
  return row * 64 + ((((col >> 3) ^ (row & 7)) << 3) | (col & 7));
}

// ---------------------------------------------------------------- convert
__global__ void cvt_kernel(const float* __restrict__ in, bf16* __restrict__ out, int n4) {
  int i = blockIdx.x * 256 + threadIdx.x;
  if (i >= n4) return;
  const float4 v = ((const float4*)in)[i];
  uint2 pk;
  pk.x = (unsigned)f2bfraw(v.x) | ((unsigned)f2bfraw(v.y) << 16);
  pk.y = (unsigned)f2bfraw(v.z) | ((unsigned)f2bfraw(v.w) << 16);
  ((uint2*)out)[i] = pk;
}

// ---------------------------------------------------------------- embedding
__global__ void embed_kernel(const int* __restrict__ x, const float* __restrict__ emb,
                             const float* __restrict__ pos, float* __restrict__ hbuf) {
  int idx = blockIdx.x * 256 + threadIdx.x;  // one float4 each; 16384*72 total
  if (idx >= 16384 * 72) return;
  int row = idx / 72, c4 = idx - row * 72;
  int tok = x[row];
  const float4 e = ((const float4*)(emb + (size_t)tok * 288))[c4];
  const float4 p = ((const float4*)(pos + (size_t)(row & 511) * 288))[c4];
  float4 o;
  o.x = e.x + p.x; o.y = e.y + p.y; o.z = e.z + p.z; o.w = e.w + p.w;
  ((float4*)hbuf)[idx] = o;
}

// ---------------------------------------------------------------- rmsnorm
// matches ref: norm = sqrt(sum(x^2)/288); y = s * x / (norm + 1e-6)
__global__ __launch_bounds__(256) void rmsnorm_kernel(const float* __restrict__ x,
                                                      const float* __restrict__ sc,
                                                      bf16* __restrict__ out) {
  int row = blockIdx.x * 4 + (threadIdx.x >> 6);
  int lane = threadIdx.x & 63;
  const float* xr = x + (size_t)row * 288;
  float v[5];
  float ss = 0.f;
#pragma unroll
  for (int j = 0; j < 4; ++j) { v[j] = xr[j * 64 + lane]; ss += v[j] * v[j]; }
  v[4] = (lane < 32) ? xr[256 + lane] : 0.f;
  ss += v[4] * v[4];
#pragma unroll
  for (int off = 32; off > 0; off >>= 1) ss += __shfl_xor(ss, off);
  float inv = 1.f / (sqrtf(ss * (1.f / 288.f)) + 1e-6f);
  bf16* orow = out + (size_t)row * 288;
#pragma unroll
  for (int j = 0; j < 4; ++j) orow[j * 64 + lane] = f2bf(v[j] * inv * sc[j * 64 + lane]);
  if (lane < 32) orow[256 + lane] = f2bf(v[4] * inv * sc[256 + lane]);
}

// ---------------------------------------------------------------- scan
// h_t = f_t*h_{t-1} + (1-f_t)*v_t ; y = g*h  (per (b,d) independent chain)
__global__ void scan_kernel(const bf16* __restrict__ gvf, bf16* __restrict__ y) {
  int i = blockIdx.x * 256 + threadIdx.x;
  if (i >= 32 * 288) return;
  int b = i / 288, d = i - b * 288;
  const bf16* base = gvf + (size_t)b * 512 * 864;
  bf16* yb = y + (size_t)b * 512 * 288 + d;
  float hs = 0.f;
#pragma unroll 4
  for (int t = 0; t < 512; ++t) {
    float g = bf2f(base[(size_t)t * 864 + d]);
    float v = bf2f(base[(size_t)t * 864 + 288 + d]);
    float f = bf2f(base[(size_t)t * 864 + 576 + d]);
    hs = f * hs + (1.f - f) * v;
    yb[(size_t)t * 288] = f2bf(g * hs);
  }
}

// ---------------------------------------------------------------- GEMM
// out[M,N] = A[M,K] @ W[N,K]^T  (W native row-major IS the B^T layout MFMA wants)
// 128x BN tile, BK=32, 4 waves (2x2), reg-staged double-buffered LDS.
template <int BN, int EPI>
__global__ __launch_bounds__(256) void gemm_kernel(const bf16* __restrict__ A,
                                                   const bf16* __restrict__ W,
                                                   void* __restrict__ outv,
                                                   int N, int K) {
  constexpr int WN = BN / 2;
  constexpr int NF = WN / 16;
  constexpr int NA = 512;            // A 16B-chunks per K-step
  constexpr int NB = BN * 32 / 8;    // W chunks
  constexpr int NTOT = NA + NB;
  constexpr int NLD = (NTOT + 255) / 256;
  __shared__ __align__(16) bf16 As[2][128 * 32];
  __shared__ __align__(16) bf16 Bs[2][BN * 32];
  const int tid = threadIdx.x;
  const int w = tid >> 6, l = tid & 63;
  const int m0 = blockIdx.x * 128;
  const int n0 = blockIdx.y * BN;
  const int nk = K >> 5;

  short8 r[NLD];
  auto loadc = [&](int kt) {
#pragma unroll
    for (int j = 0; j < NLD; ++j) {
      int c = tid + j * 256;
      if (NTOT == NLD * 256 || c < NTOT) {
        const bf16* g;
        if (c < NA) {
          int row = c >> 2, sl = c & 3;
          g = A + (size_t)(m0 + row) * K + kt * 32 + sl * 8;
        } else {
          int c2 = c - NA;
          int row = c2 >> 2, sl = c2 & 3;
          g = W + (size_t)(n0 + row) * K + kt * 32 + sl * 8;
        }
        r[j] = *(const short8*)g;
      }
    }
  };
  auto storec = [&](int buf) {
#pragma unroll
    for (int j = 0; j < NLD; ++j) {
      int c = tid + j * 256;
      if (NTOT == NLD * 256 || c < NTOT) {
        if (c < NA) {
          int row = c >> 2, sl = c & 3;
          *(short8*)&As[buf][swz64(row, sl * 8)] = r[j];
        } else {
          int c2 = c - NA;
          int row = c2 >> 2, sl = c2 & 3;
          *(short8*)&Bs[buf][swz64(row, sl * 8)] = r[j];
        }
      }
    }
  };

  f32x4 acc[4][NF];
#pragma unroll
  for (int a = 0; a < 4; ++a)
#pragma unroll
    for (int b = 0; b < NF; ++b) acc[a][b] = (f32x4){0.f, 0.f, 0.f, 0.f};

  loadc(0);
  storec(0);
  __syncthreads();
  for (int kt = 0; kt < nk; ++kt) {
    int cur = kt & 1;
    if (kt + 1 < nk) loadc(kt + 1);  // issue next-tile global loads early
    short8 af[4], bfr[NF];
#pragma unroll
    for (int mf = 0; mf < 4; ++mf)
      af[mf] = *(const short8*)&As[cur][swz64((w >> 1) * 64 + mf * 16 + (l & 15), (l >> 4) * 8)];
#pragma unroll
    for (int nf = 0; nf < NF; ++nf)
      bfr[nf] = *(const short8*)&Bs[cur][swz64((w & 1) * WN + nf * 16 + (l & 15), (l >> 4) * 8)];
#pragma unroll
    for (int mf = 0; mf < 4; ++mf)
#pragma unroll
      for (int nf = 0; nf < NF; ++nf)
        acc[mf][nf] = __builtin_amdgcn_mfma_f32_16x16x32_bf16(af[mf], bfr[nf], acc[mf][nf], 0, 0, 0);
    if (kt + 1 < nk) storec(cur ^ 1);  // write-late into the other buffer
    __syncthreads();
  }

#pragma unroll
  for (int mf = 0; mf < 4; ++mf) {
#pragma unroll
    for (int nf = 0; nf < NF; ++nf) {
#pragma unroll
      for (int rr = 0; rr < 4; ++rr) {
        int row = m0 + (w >> 1) * 64 + mf * 16 + (l >> 4) * 4 + rr;
        int col = n0 + (w & 1) * WN + nf * 16 + (l & 15);
        float v = acc[mf][nf][rr];
        size_t o = (size_t)row * N + col;
        if (EPI == EPI_BF16) {
          ((bf16*)outv)[o] = f2bf(v);
        } else if (EPI == EPI_GVF) {
          float z;
          if (col < 288) z = 1.f / (1.f + __expf(-v));           // g = sigmoid
          else if (col < 576) z = v;                              // v raw
          else z = 1.f / (1.f + __expf(-(v - 1.f)));              // f = sigmoid(x-1)
          ((bf16*)outv)[o] = f2bf(z);
        } else if (EPI == EPI_RES) {
          ((float*)outv)[o] += v;  // out==residual buffer h
        } else {
          ((float*)outv)[o] = v;
        }
      }
    }
  }
}

// ---------------------------------------------------------------- gate+up fused
__global__ __launch_bounds__(256) void gateup_kernel(const bf16* __restrict__ A,
                                                     const bf16* __restrict__ Wg,
                                                     const bf16* __restrict__ Wu,
                                                     bf16* __restrict__ out, int N, int K) {
  constexpr int WN = 48, NF = 3;
  constexpr int NA = 512, NB = 384;  // total 1280 = 5*256 exact
  __shared__ __align__(16) bf16 As[2][128 * 32];
  __shared__ __align__(16) bf16 Bg[2][96 * 32];
  __shared__ __align__(16) bf16 Bu[2][96 * 32];
  const int tid = threadIdx.x;
  const int w = tid >> 6, l = tid & 63;
  const int m0 = blockIdx.x * 128;
  const int n0 = blockIdx.y * 96;
  const int nk = K >> 5;

  short8 r[5];
  auto loadc = [&](int kt) {
#pragma unroll
    for (int j = 0; j < 5; ++j) {
      int c = tid + j * 256;
      const bf16* g;
      if (c < NA) {
        int row = c >> 2, sl = c & 3;
        g = A + (size_t)(m0 + row) * K + kt * 32 + sl * 8;
      } else if (c < NA + NB) {
        int c2 = c - NA;
        int row = c2 >> 2, sl = c2 & 3;
        g = Wg + (size_t)(n0 + row) * K + kt * 32 + sl * 8;
      } else {
        int c2 = c - NA - NB;
        int row = c2 >> 2, sl = c2 & 3;
        g = Wu + (size_t)(n0 + row) * K + kt * 32 + sl * 8;
      }
      r[j] = *(const short8*)g;
    }
  };
  auto storec = [&](int buf) {
#pragma unroll
    for (int j = 0; j < 5; ++j) {
      int c = tid + j * 256;
      if (c < NA) {
        int row = c >> 2, sl = c & 3;
        *(short8*)&As[buf][swz64(row, sl * 8)] = r[j];
      } else if (c < NA + NB) {
        int c2 = c - NA;
        int row = c2 >> 2, sl = c2 & 3;
        *(short8*)&Bg[buf][swz64(row, sl * 8)] = r[j];
      } else {
        int c2 = c - NA - NB;
        int row = c2 >> 2, sl = c2 & 3;
        *(short8*)&Bu[buf][swz64(row, sl * 8)] = r[j];
      }
    }
  };

  f32x4 accg[4][NF], accu[4][NF];
#pragma unroll
  for (int a = 0; a < 4; ++a)
#pragma unroll
    for (int b = 0; b < NF; ++b) {
      accg[a][b] = (f32x4){0.f, 0.f, 0.f, 0.f};
      accu[a][b] = (f32x4){0.f, 0.f, 0.f, 0.f};
    }

  loadc(0);
  storec(0);
  __syncthreads();
  for (int kt = 0; kt < nk; ++kt) {
    int cur = kt & 1;
    if (kt + 1 < nk) loadc(kt + 1);
    short8 af[4], bg[NF], bu[NF];
#pragma unroll
    for (int mf = 0; mf < 4; ++mf)
      af[mf] = *(const short8*)&As[cur][swz64((w >> 1) * 64 + mf * 16 + (l & 15), (l >> 4) * 8)];
#pragma unroll
    for (int nf = 0; nf < NF; ++nf) {
      bg[nf] = *(const short8*)&Bg[cur][swz64((w & 1) * WN + nf * 16 + (l & 15), (l >> 4) * 8)];
      bu[nf] = *(const short8*)&Bu[cur][swz64((w & 1) * WN + nf * 16 + (l & 15), (l >> 4) * 8)];
    }
#pragma unroll
    for (int mf = 0; mf < 4; ++mf)
#pragma unroll
      for (int nf = 0; nf < NF; ++nf) {
        accg[mf][nf] = __builtin_amdgcn_mfma_f32_16x16x32_bf16(af[mf], bg[nf], accg[mf][nf], 0, 0, 0);
        accu[mf][nf] = __builtin_amdgcn_mfma_f32_16x16x32_bf16(af[mf], bu[nf], accu[mf][nf], 0, 0, 0);
      }
    if (kt + 1 < nk) storec(cur ^ 1);
    __syncthreads();
  }

#pragma unroll
  for (int mf = 0; mf < 4; ++mf)
#pragma unroll
    for (int nf = 0; nf < NF; ++nf)
#pragma unroll
      for (int rr = 0; rr < 4; ++rr) {
        int row = m0 + (w >> 1) * 64 + mf * 16 + (l >> 4) * 4 + rr;
        int col = n0 + (w & 1) * WN + nf * 16 + (l & 15);
        float g = accg[mf][nf][rr], u = accu[mf][nf][rr];
        float s = g / (1.f + __expf(-g));  // silu
        out[(size_t)row * N + col] = f2bf(s * u);
      }
}

// ---------------------------------------------------------------- flash attention
// causal, H=8, HD=36 (padded to 64 in LDS), one block per (b, h, 64-row q-tile)
__global__ __launch_bounds__(256) void attn_kernel(const bf16* __restrict__ qkv,
                                                   bf16* __restrict__ y) {
  const int bid = blockIdx.x;
  const int qb = bid & 7, hh = (bid >> 3) & 7, b = bid >> 6;
  const int tid = threadIdx.x, w = tid >> 6, l = tid & 63;
  __shared__ __align__(16) bf16 Qs[64 * 64];
  __shared__ __align__(16) bf16 Ks[64 * 64];
  __shared__ __align__(16) bf16 Vt[48 * 64];
  __shared__ __align__(16) bf16 Ps[64 * 64];
  const size_t bbase = (size_t)b * 512 * 864;

  for (int idx = tid; idx < 64 * 64; idx += 256) {
    ((unsigned short*)Qs)[idx] = 0;
    ((unsigned short*)Ks)[idx] = 0;
  }
  for (int idx = tid; idx < 48 * 64; idx += 256) ((unsigned short*)Vt)[idx] = 0;

  const bf16* qp = qkv + bbase + (size_t)(qb * 64) * 864 + hh * 36;
  for (int idx = tid; idx < 64 * 36; idx += 256) {
    int row = idx / 36, c = idx - row * 36;
    Qs[swz128(row, c)] = qp[(size_t)row * 864 + c];
  }
  __syncthreads();

  f32x4 oacc[3];
#pragma unroll
  for (int f = 0; f < 3; ++f) oacc[f] = (f32x4){0.f, 0.f, 0.f, 0.f};
  float mprev[4] = {-1e30f, -1e30f, -1e30f, -1e30f};
  float lsum[4] = {0.f, 0.f, 0.f, 0.f};
  const int qrow_base = qb * 64 + w * 16;

  for (int kt = 0; kt <= qb; ++kt) {
    const bf16* kp = qkv + bbase + (size_t)(kt * 64) * 864 + 288 + hh * 36;
    const bf16* vp = qkv + bbase + (size_t)(kt * 64) * 864 + 576 + hh * 36;
    for (int idx = tid; idx < 64 * 36; idx += 256) {
      int row = idx / 36, c = idx - row * 36;
      Ks[swz128(row, c)] = kp[(size_t)row * 864 + c];
      Vt[swz128(c, row)] = vp[(size_t)row * 864 + c];  // transposed stage
    }
    __syncthreads();

    f32x4 sacc[4];
#pragma unroll
    for (int n = 0; n < 4; ++n) sacc[n] = (f32x4){0.f, 0.f, 0.f, 0.f};
#pragma unroll
    for (int s = 0; s < 2; ++s) {
      short8 aq = *(const short8*)&Qs[swz128(w * 16 + (l & 15), s * 32 + (l >> 4) * 8)];
#pragma unroll
      for (int n = 0; n < 4; ++n) {
        short8 bk = *(const short8*)&Ks[swz128(n * 16 + (l & 15), s * 32 + (l >> 4) * 8)];
        sacc[n] = __builtin_amdgcn_mfma_f32_16x16x32_bf16(aq, bk, sacc[n], 0, 0, 0);
      }
    }

    const bool diag = (kt == qb);
    float mt[4];
#pragma unroll
    for (int rr = 0; rr < 4; ++rr) {
      int qg = qrow_base + (l >> 4) * 4 + rr;
      float mx = -1e30f;
#pragma unroll
      for (int n = 0; n < 4; ++n) {
        float sv = sacc[n][rr] * (1.f / 6.f);
        if (diag) {
          int kg = kt * 64 + n * 16 + (l & 15);
          if (kg > qg) sv = -1e30f;
        }
        sacc[n][rr] = sv;
        mx = fmaxf(mx, sv);
      }
      mt[rr] = mx;
    }
#pragma unroll
    for (int off = 1; off < 16; off <<= 1)
#pragma unroll
      for (int rr = 0; rr < 4; ++rr) mt[rr] = fmaxf(mt[rr], __shfl_xor(mt[rr], off));

    float alpha[4], rs[4];
#pragma unroll
    for (int rr = 0; rr < 4; ++rr) {
      float mn = fmaxf(mprev[rr], mt[rr]);
      alpha[rr] = exp2f((mprev[rr] - mn) * LOG2E);
      mprev[rr] = mn;
      float ps = 0.f;
#pragma unroll
      for (int n = 0; n < 4; ++n) {
        float p = exp2f((sacc[n][rr] - mn) * LOG2E);
        sacc[n][rr] = p;
        ps += p;
      }
      rs[rr] = ps;
    }
#pragma unroll
    for (int off = 1; off < 16; off <<= 1)
#pragma unroll
      for (int rr = 0; rr < 4; ++rr) rs[rr] += __shfl_xor(rs[rr], off);
#pragma unroll
    for (int rr = 0; rr < 4; ++rr) lsum[rr] = lsum[rr] * alpha[rr] + rs[rr];
#pragma unroll
    for (int f = 0; f < 3; ++f)
#pragma unroll
      for (int rr = 0; rr < 4; ++rr) oacc[f][rr] *= alpha[rr];

#pragma unroll
    for (int n = 0; n < 4; ++n)
#pragma unroll
      for (int rr = 0; rr < 4; ++rr)
        Ps[swz128(w * 16 + (l >> 4) * 4 + rr, n * 16 + (l & 15))] = f2bf(sacc[n][rr]);
    __syncthreads();

#pragma unroll
    for (int s = 0; s < 2; ++s) {
      short8 ap = *(const short8*)&Ps[swz128(w * 16 + (l & 15), s * 32 + (l >> 4) * 8)];
#pragma unroll
      for (int f = 0; f < 3; ++f) {
        short8 bv = *(const short8*)&Vt[swz128(f * 16 + (l & 15), s * 32 + (l >> 4) * 8)];
        oacc[f] = __builtin_amdgcn_mfma_f32_16x16x32_bf16(ap, bv, oacc[f], 0, 0, 0);
      }
    }
    __syncthreads();
  }

#pragma unroll
  for (int rr = 0; rr < 4; ++rr) {
    float inv = 1.f / lsum[rr];
    int row = b * 512 + qb * 64 + w * 16 + (l >> 4) * 4 + rr;
    bf16* yr = y + (size_t)row * 288 + hh * 36;
#pragma unroll
    for (int f = 0; f < 3; ++f) {
      int col = f * 16 + (l & 15);
      if (col < 36) yr[col] = f2bf(oacc[f][rr] * inv);
    }
  }
}

// ---------------------------------------------------------------- launcher
extern "C" void kernel_launch(void* const* d_in, const int* in_sizes, int n_in,
                              void* d_out, int out_size, void* d_ws, size_t ws_size,
                              hipStream_t stream) {
  (void)in_sizes; (void)n_in; (void)out_size; (void)ws_size;
  const int* x = (const int*)d_in[0];
  const float* emb = (const float*)d_in[1];
  const float* pos = (const float*)d_in[2];
  const float* aqkv = (const float*)d_in[3];
  const float* aout = (const float*)d_in[4];
  const float* anorm = (const float*)d_in[5];
  const float* rin = (const float*)d_in[6];
  const float* rout = (const float*)d_in[7];
  const float* rnorm = (const float*)d_in[8];
  const float* fgate = (const float*)d_in[9];
  const float* fup = (const float*)d_in[10];
  const float* fdown = (const float*)d_in[11];
  const float* fnorm = (const float*)d_in[12];
  const float* finalnorm = (const float*)d_in[13];

  char* ws = (char*)d_ws;
  size_t off = 0;
  auto alloc = [&](size_t bytes) -> char* {
    char* p = ws + off;
    off += (bytes + 255) & ~(size_t)255;
    return p;
  };
  bf16* wqkv = (bf16*)alloc(4ull * 864 * 288 * 2);
  bf16* wao = (bf16*)alloc(4ull * 288 * 288 * 2);
  bf16* wrin = (bf16*)alloc(10ull * 864 * 288 * 2);
  bf16* wrout = (bf16*)alloc(10ull * 288 * 288 * 2);
  bf16* wg = (bf16*)alloc(14ull * 864 * 288 * 2);
  bf16* wu = (bf16*)alloc(14ull * 864 * 288 * 2);
  bf16* wd = (bf16*)alloc(14ull * 288 * 864 * 2);
  bf16* wemb = (bf16*)alloc(4096ull * 288 * 2);
  float* hbuf = (float*)alloc(16384ull * 288 * 4);
  bf16* xn = (bf16*)alloc(16384ull * 288 * 2);
  bf16* gvf = (bf16*)alloc(16384ull * 864 * 2);
  bf16* ybuf = (bf16*)alloc(16384ull * 288 * 2);

  auto cvt = [&](const float* src, bf16* dst, size_t n) {
    int n4 = (int)(n / 4);
    cvt_kernel<<<(n4 + 255) / 256, 256, 0, stream>>>(src, dst, n4);
  };
  cvt(aqkv, wqkv, 4ull * 864 * 288);
  cvt(aout, wao, 4ull * 288 * 288);
  cvt(rin, wrin, 10ull * 864 * 288);
  cvt(rout, wrout, 10ull * 288 * 288);
  cvt(fgate, wg, 14ull * 864 * 288);
  cvt(fup, wu, 14ull * 864 * 288);
  cvt(fdown, wd, 14ull * 288 * 864);
  cvt(emb, wemb, 4096ull * 288);

  embed_kernel<<<(16384 * 72) / 256, 256, 0, stream>>>(x, emb, pos, hbuf);

  int ai = 0, ri = 0;
  for (int i = 0; i < 14; ++i) {
    const bool isattn = ((i + 1) % 3 == 0);
    const float* mnorm = isattn ? (anorm + ai * 288) : (rnorm + ri * 288);
    rmsnorm_kernel<<<4096, 256, 0, stream>>>(hbuf, mnorm, xn);
    if (isattn) {
      gemm_kernel<96, EPI_BF16><<<dim3(128, 9), 256, 0, stream>>>(
          xn, wqkv + (size_t)ai * 864 * 288, gvf, 864, 288);
      attn_kernel<<<2048, 256, 0, stream>>>(gvf, ybuf);
      gemm_kernel<96, EPI_RES><<<dim3(128, 3), 256, 0, stream>>>(
          ybuf, wao + (size_t)ai * 288 * 288, hbuf, 288, 288);
      ++ai;
    } else {
      gemm_kernel<96, EPI_GVF><<<dim3(128, 9), 256, 0, stream>>>(
          xn, wrin + (size_t)ri * 864 * 288, gvf, 864, 288);
      scan_kernel<<<36, 256, 0, stream>>>(gvf, ybuf);
      gemm_kernel<96, EPI_RES><<<dim3(128, 3), 256, 0, stream>>>(
          ybuf, wrout + (size_t)ri * 288 * 288, hbuf, 288, 288);
      ++ri;
    }
    rmsnorm_kernel<<<4096, 256, 0, stream>>>(hbuf, fnorm + i * 288, xn);
    gateup_kernel<<<dim3(128, 9), 256, 0, stream>>>(
        xn, wg + (size_t)i * 864 * 288, wu + (size_t)i * 864 * 288, gvf, 864, 288);
    gemm_kernel<96, EPI_RES><<<dim3(128, 3), 256, 0, stream>>>(
        gvf, wd + (size_t)i * 288 * 864, hbuf, 288, 864);
  }
  rmsnorm_kernel<<<4096, 256, 0, stream>>>(hbuf, finalnorm, xn);
  gemm_kernel<128, EPI_F32><<<dim3(128, 32), 256, 0, stream>>>(
      xn, wemb, d_out, 4096, 288);
}

// Round 2
// 2646.114 us; speedup vs baseline: 1.1868x; 1.1868x over previous
//
#include <hip/hip_runtime.h>
#include <hip/hip_bf16.h>
#include <math.h>
#include <stdint.h>

using bf16 = __hip_bfloat16;
typedef __attribute__((ext_vector_type(8))) short short8;
typedef __attribute__((ext_vector_type(4))) float f32x4;

#define LOG2E 1.44269504088896340736f

enum { EPI_BF16 = 0, EPI_GVF = 1, EPI_F32 = 3 };

__device__ __forceinline__ float bf2f(bf16 v) { return __bfloat162float(v); }
__device__ __forceinline__ bf16 f2bf(float v) { return __float2bfloat16(v); }
__device__ __forceinline__ unsigned short f2bfraw(float f) {
  bf16 h = __float2bfloat16(f);
  unsigned short u;
  __builtin_memcpy(&u, &h, 2);
  return u;
}
__device__ __forceinline__ float braw2f(unsigned short u) {
  unsigned x = (unsigned)u << 16;
  float f;
  __builtin_memcpy(&f, &x, 4);
  return f;
}

// LDS swizzle for 32-col (64B-row) bf16 tiles: chunk ^= (row>>1)&3.
// Gives 2-way (free) bank aliasing on 16-lane-per-column ds_read_b128.
__device__ __forceinline__ int swz64(int row, int col) {
  return row * 32 + ((((col >> 3) ^ ((row >> 1) & 3)) << 3) | (col & 7));
}
__device__ __forceinline__ int swz128(int row, int col) {
  return row * 64 + ((((col >> 3) ^ (row & 7)) << 3) | (col & 7));
}

// global -> LDS direct (width 16). dst is wave-uniform; lane l fills dst+16*l.
__device__ __forceinline__ void gload16(const bf16* src, bf16* dst) {
  __builtin_amdgcn_global_load_lds(
      (const __attribute__((address_space(1))) void*)src,
      (__attribute__((address_space(3))) void*)dst, 16, 0, 0);
}

// ---------------------------------------------------------------- convert
__global__ void cvt_kernel(const float* __restrict__ in, bf16* __restrict__ out, int n4) {
  int i = blockIdx.x * 256 + threadIdx.x;
  if (i >= n4) return;
  const float4 v = ((const float4*)in)[i];
  uint2 pk;
  pk.x = (unsigned)f2bfraw(v.x) | ((unsigned)f2bfraw(v.y) << 16);
  pk.y = (unsigned)f2bfraw(v.z) | ((unsigned)f2bfraw(v.w) << 16);
  ((uint2*)out)[i] = pk;
}

// ---------------------------------------------------------------- embed + norm
// h = emb[tok] + pos[t]; hbuf = h; xn = rmsnorm(h) * sc   (one wave per row)
__global__ __launch_bounds__(256) void embed_norm_kernel(const int* __restrict__ x,
                                                         const float* __restrict__ emb,
                                                         const float* __restrict__ pos,
                                                         const float* __restrict__ sc,
                                                         float* __restrict__ hbuf,
                                                         bf16* __restrict__ xn) {
  int row = blockIdx.x * 4 + (threadIdx.x >> 6);
  int lane = threadIdx.x & 63;
  int tok = x[row];
  const float* e = emb + (size_t)tok * 288;
  const float* p = pos + (size_t)(row & 511) * 288;
  float v[5];
  float ss = 0.f;
#pragma unroll
  for (int j = 0; j < 4; ++j) {
    v[j] = e[j * 64 + lane] + p[j * 64 + lane];
    ss += v[j] * v[j];
  }
  v[4] = (lane < 32) ? (e[256 + lane] + p[256 + lane]) : 0.f;
  ss += v[4] * v[4];
#pragma unroll
  for (int off = 32; off > 0; off >>= 1) ss += __shfl_xor(ss, off);
  float inv = 1.f / (sqrtf(ss * (1.f / 288.f)) + 1e-6f);
  float* hr = hbuf + (size_t)row * 288;
  bf16* xr = xn + (size_t)row * 288;
#pragma unroll
  for (int j = 0; j < 4; ++j) {
    hr[j * 64 + lane] = v[j];
    xr[j * 64 + lane] = f2bf(v[j] * inv * sc[j * 64 + lane]);
  }
  if (lane < 32) {
    hr[256 + lane] = v[4];
    xr[256 + lane] = f2bf(v[4] * inv * sc[256 + lane]);
  }
}

// ---------------------------------------------------------------- scan (chunked)
// 16 chunks x 32 steps; 2 chains per thread (d, d+1).
__global__ __launch_bounds__(64) void scanA_kernel(const bf16* __restrict__ gvf,
                                                   float* __restrict__ Ap,
                                                   float* __restrict__ Bp) {
  int g = blockIdx.x * 64 + threadIdx.x;  // 0..4607
  int c = blockIdx.y;                     // 0..15
  int b = g / 144, dp = g - b * 144;
  const bf16* base = gvf + (size_t)b * 512 * 864 + (size_t)c * 32 * 864 + dp * 2;
  float A0 = 1.f, A1 = 1.f, B0 = 0.f, B1 = 0.f;
#pragma unroll 4
  for (int t = 0; t < 32; ++t) {
    unsigned vv = *(const unsigned*)(base + (size_t)t * 864 + 288);
    unsigned ff = *(const unsigned*)(base + (size_t)t * 864 + 576);
    float v0 = braw2f((unsigned short)vv), v1 = braw2f((unsigned short)(vv >> 16));
    float f0 = braw2f((unsigned short)ff), f1 = braw2f((unsigned short)(ff >> 16));
    B0 = f0 * B0 + (1.f - f0) * v0;
    B1 = f1 * B1 + (1.f - f1) * v1;
    A0 *= f0;
    A1 *= f1;
  }
  int half = b * 144 + dp;
  ((float2*)(Ap + (size_t)c * 9216))[half] = make_float2(A0, A1);
  ((float2*)(Bp + (size_t)c * 9216))[half] = make_float2(B0, B1);
}

__global__ __launch_bounds__(64) void scanC_kernel(const bf16* __restrict__ gvf,
                                                   const float* __restrict__ Ap,
                                                   const float* __restrict__ Bp,
                                                   bf16* __restrict__ y) {
  int g = blockIdx.x * 64 + threadIdx.x;
  int c = blockIdx.y;
  int b = g / 144, dp = g - b * 144;
  int half = b * 144 + dp;
  float h0 = 0.f, h1 = 0.f;
  for (int cc = 0; cc < c; ++cc) {
    float2 a = ((const float2*)(Ap + (size_t)cc * 9216))[half];
    float2 bb = ((const float2*)(Bp + (size_t)cc * 9216))[half];
    h0 = bb.x + a.x * h0;
    h1 = bb.y + a.y * h1;
  }
  const bf16* base = gvf + (size_t)b * 512 * 864 + (size_t)c * 32 * 864 + dp * 2;
  bf16* yb = y + (size_t)b * 512 * 288 + (size_t)c * 32 * 288 + dp * 2;
#pragma unroll 4
  for (int t = 0; t < 32; ++t) {
    unsigned gg = *(const unsigned*)(base + (size_t)t * 864);
    unsigned vv = *(const unsigned*)(base + (size_t)t * 864 + 288);
    unsigned ff = *(const unsigned*)(base + (size_t)t * 864 + 576);
    float g0 = braw2f((unsigned short)gg), g1 = braw2f((unsigned short)(gg >> 16));
    float v0 = braw2f((unsigned short)vv), v1 = braw2f((unsigned short)(vv >> 16));
    float f0 = braw2f((unsigned short)ff), f1 = braw2f((unsigned short)(ff >> 16));
    h0 = f0 * h0 + (1.f - f0) * v0;
    h1 = f1 * h1 + (1.f - f1) * v1;
    unsigned o = (unsigned)f2bfraw(g0 * h0) | ((unsigned)f2bfraw(g1 * h1) << 16);
    *(unsigned*)(yb + (size_t)t * 288) = o;
  }
}

// ---------------------------------------------------------------- GEMM (tiled)
// out[M,N] = A[M,K] @ W[N,K]^T. 128 x BN tile, BK=32, 4 waves (2x2),
// global_load_lds staging (linear dest, inverse-swizzled source).
template <int BN, int EPI>
__global__ __launch_bounds__(256) void gemm_kernel(const bf16* __restrict__ A,
                                                   const bf16* __restrict__ W,
                                                   void* __restrict__ outv,
                                                   int N, int K) {
  constexpr int WN = BN / 2;
  constexpr int NF = WN / 16;
  constexpr int TC = 8 + BN / 16;  // wave-chunks per K-step (16 rows each)
  __shared__ __align__(16) bf16 As[2][128 * 32];
  __shared__ __align__(16) bf16 Bs[2][BN * 32];
  const int tid = threadIdx.x;
  const int w = tid >> 6, l = tid & 63;
  const int m0 = blockIdx.x * 128;
  const int n0 = blockIdx.y * BN;
  const int nk = K >> 5;
  const int lrow = l >> 2, lslot = l & 3;

  auto stage = [&](int buf, int kt) {
    for (int wc = w; wc < TC; wc += 4) {
      const bf16* src;
      bf16* dst;
      int row;
      if (wc < 8) {
        row = wc * 16 + lrow;
        src = A + (size_t)(m0 + row) * K;
        dst = &As[buf][wc * 512];
      } else {
        row = (wc - 8) * 16 + lrow;
        src = W + (size_t)(n0 + row) * K;
        dst = &Bs[buf][(wc - 8) * 512];
      }
      int slot = lslot ^ ((row >> 1) & 3);
      gload16(src + kt * 32 + slot * 8, dst);
    }
  };

  f32x4 acc[4][NF];
#pragma unroll
  for (int a = 0; a < 4; ++a)
#pragma unroll
    for (int b = 0; b < NF; ++b) acc[a][b] = (f32x4){0.f, 0.f, 0.f, 0.f};

  stage(0, 0);
  __syncthreads();
  for (int kt = 0; kt < nk; ++kt) {
    int cur = kt & 1;
    if (kt + 1 < nk) stage(cur ^ 1, kt + 1);
    short8 af[4], bfr[NF];
#pragma unroll
    for (int mf = 0; mf < 4; ++mf)
      af[mf] = *(const short8*)&As[cur][swz64((w >> 1) * 64 + mf * 16 + (l & 15), (l >> 4) * 8)];
#pragma unroll
    for (int nf = 0; nf < NF; ++nf)
      bfr[nf] = *(const short8*)&Bs[cur][swz64((w & 1) * WN + nf * 16 + (l & 15), (l >> 4) * 8)];
#pragma unroll
    for (int mf = 0; mf < 4; ++mf)
#pragma unroll
      for (int nf = 0; nf < NF; ++nf)
        acc[mf][nf] = __builtin_amdgcn_mfma_f32_16x16x32_bf16(af[mf], bfr[nf], acc[mf][nf], 0, 0, 0);
    __syncthreads();
  }

#pragma unroll
  for (int mf = 0; mf < 4; ++mf) {
#pragma unroll
    for (int nf = 0; nf < NF; ++nf) {
#pragma unroll
      for (int rr = 0; rr < 4; ++rr) {
        int row = m0 + (w >> 1) * 64 + mf * 16 + (l >> 4) * 4 + rr;
        int col = n0 + (w & 1) * WN + nf * 16 + (l & 15);
        float v = acc[mf][nf][rr];
        size_t o = (size_t)row * N + col;
        if (EPI == EPI_BF16) {
          ((bf16*)outv)[o] = f2bf(v);
        } else if (EPI == EPI_GVF) {
          float z;
          if (col < 288) z = 1.f / (1.f + __expf(-v));       // g = sigmoid
          else if (col < 576) z = v;                          // v raw
          else z = 1.f / (1.f + __expf(-(v - 1.f)));          // f = sigmoid(x-1)
          ((bf16*)outv)[o] = f2bf(z);
        } else {
          ((float*)outv)[o] = v;
        }
      }
    }
  }
}

// ---------------------------------------------------------------- GEMM full-row
// out-proj / down-proj: 64 x 288 tile (full row), epilogue does residual add +
// rmsnorm; writes hbuf (fp32) and xn = norm(h)*scale (bf16). 4 waves 2Mx2N.
__global__ __launch_bounds__(256) void gemm_row_kernel(const bf16* __restrict__ A,
                                                       const bf16* __restrict__ W,
                                                       float* __restrict__ hbuf,
                                                       bf16* __restrict__ xn,
                                                       const float* __restrict__ scale,
                                                       int K) {
  __shared__ __align__(16) bf16 As[2][64 * 32];
  __shared__ __align__(16) bf16 Bs[2][288 * 32];
  __shared__ float ssx[2][64];
  const int tid = threadIdx.x;
  const int w = tid >> 6, l = tid & 63;
  const int m0 = blockIdx.x * 64;
  const int nk = K >> 5;
  const int lrow = l >> 2, lslot = l & 3;

  auto stage = [&](int buf, int kt) {
    for (int wc = w; wc < 22; wc += 4) {
      const bf16* src;
      bf16* dst;
      int row;
      if (wc < 4) {
        row = wc * 16 + lrow;
        src = A + (size_t)(m0 + row) * K;
        dst = &As[buf][wc * 512];
      } else {
        row = (wc - 4) * 16 + lrow;
        src = W + (size_t)row * K;
        dst = &Bs[buf][(wc - 4) * 512];
      }
      int slot = lslot ^ ((row >> 1) & 3);
      gload16(src + kt * 32 + slot * 8, dst);
    }
  };

  f32x4 acc[2][9];
#pragma unroll
  for (int a = 0; a < 2; ++a)
#pragma unroll
    for (int b = 0; b < 9; ++b) acc[a][b] = (f32x4){0.f, 0.f, 0.f, 0.f};

  stage(0, 0);
  __syncthreads();
  for (int kt = 0; kt < nk; ++kt) {
    int cur = kt & 1;
    if (kt + 1 < nk) stage(cur ^ 1, kt + 1);
    short8 af[2];
#pragma unroll
    for (int mf = 0; mf < 2; ++mf)
      af[mf] = *(const short8*)&As[cur][swz64((w >> 1) * 32 + mf * 16 + (l & 15), (l >> 4) * 8)];
#pragma unroll
    for (int nf = 0; nf < 9; ++nf) {
      short8 bv = *(const short8*)&Bs[cur][swz64((w & 1) * 144 + nf * 16 + (l & 15), (l >> 4) * 8)];
      acc[0][nf] = __builtin_amdgcn_mfma_f32_16x16x32_bf16(af[0], bv, acc[0][nf], 0, 0, 0);
      acc[1][nf] = __builtin_amdgcn_mfma_f32_16x16x32_bf16(af[1], bv, acc[1][nf], 0, 0, 0);
    }
    __syncthreads();
  }

  // epilogue: v = acc + residual; row sum-sq; hbuf = v; xn = v*invnorm*scale
  float ss[2][4];
#pragma unroll
  for (int mf = 0; mf < 2; ++mf)
#pragma unroll
    for (int rr = 0; rr < 4; ++rr) ss[mf][rr] = 0.f;

#pragma unroll
  for (int mf = 0; mf < 2; ++mf)
#pragma unroll
    for (int nf = 0; nf < 9; ++nf)
#pragma unroll
      for (int rr = 0; rr < 4; ++rr) {
        int rowl = (w >> 1) * 32 + mf * 16 + (l >> 4) * 4 + rr;
        int col = (w & 1) * 144 + nf * 16 + (l & 15);
        size_t o = (size_t)(m0 + rowl) * 288 + col;
        float v = acc[mf][nf][rr] + hbuf[o];
        hbuf[o] = v;
        acc[mf][nf][rr] = v;
        ss[mf][rr] += v * v;
      }
#pragma unroll
  for (int off = 1; off < 16; off <<= 1)
#pragma unroll
    for (int mf = 0; mf < 2; ++mf)
#pragma unroll
      for (int rr = 0; rr < 4; ++rr) ss[mf][rr] += __shfl_xor(ss[mf][rr], off);
  if ((l & 15) == 0) {
#pragma unroll
    for (int mf = 0; mf < 2; ++mf)
#pragma unroll
      for (int rr = 0; rr < 4; ++rr)
        ssx[w & 1][(w >> 1) * 32 + mf * 16 + (l >> 4) * 4 + rr] = ss[mf][rr];
  }
  __syncthreads();
  float inv[2][4];
#pragma unroll
  for (int mf = 0; mf < 2; ++mf)
#pragma unroll
    for (int rr = 0; rr < 4; ++rr) {
      int rowl = (w >> 1) * 32 + mf * 16 + (l >> 4) * 4 + rr;
      float tot = ssx[0][rowl] + ssx[1][rowl];
      inv[mf][rr] = 1.f / (sqrtf(tot * (1.f / 288.f)) + 1e-6f);
    }
#pragma unroll
  for (int nf = 0; nf < 9; ++nf) {
    int col = (w & 1) * 144 + nf * 16 + (l & 15);
    float sc = scale[col];
#pragma unroll
    for (int mf = 0; mf < 2; ++mf)
#pragma unroll
      for (int rr = 0; rr < 4; ++rr) {
        int rowl = (w >> 1) * 32 + mf * 16 + (l >> 4) * 4 + rr;
        size_t o = (size_t)(m0 + rowl) * 288 + col;
        xn[o] = f2bf(acc[mf][nf][rr] * inv[mf][rr] * sc);
      }
  }
}

// ---------------------------------------------------------------- gate+up fused
__global__ __launch_bounds__(256) void gateup_kernel(const bf16* __restrict__ A,
                                                     const bf16* __restrict__ Wg,
                                                     const bf16* __restrict__ Wu,
                                                     bf16* __restrict__ out, int N, int K) {
  constexpr int WN = 48, NF = 3;
  __shared__ __align__(16) bf16 As[2][128 * 32];
  __shared__ __align__(16) bf16 Bg[2][96 * 32];
  __shared__ __align__(16) bf16 Bu[2][96 * 32];
  const int tid = threadIdx.x;
  const int w = tid >> 6, l = tid & 63;
  const int m0 = blockIdx.x * 128;
  const int n0 = blockIdx.y * 96;
  const int nk = K >> 5;
  const int lrow = l >> 2, lslot = l & 3;

  auto stage = [&](int buf, int kt) {
    for (int wc = w; wc < 20; wc += 4) {
      const bf16* src;
      bf16* dst;
      int row;
      if (wc < 8) {
        row = wc * 16 + lrow;
        src = A + (size_t)(m0 + row) * K;
        dst = &As[buf][wc * 512];
      } else if (wc < 14) {
        row = (wc - 8) * 16 + lrow;
        src = Wg + (size_t)(n0 + row) * K;
        dst = &Bg[buf][(wc - 8) * 512];
      } else {
        row = (wc - 14) * 16 + lrow;
        src = Wu + (size_t)(n0 + row) * K;
        dst = &Bu[buf][(wc - 14) * 512];
      }
      int slot = lslot ^ ((row >> 1) & 3);
      gload16(src + kt * 32 + slot * 8, dst);
    }
  };

  f32x4 accg[4][NF], accu[4][NF];
#pragma unroll
  for (int a = 0; a < 4; ++a)
#pragma unroll
    for (int b = 0; b < NF; ++b) {
      accg[a][b] = (f32x4){0.f, 0.f, 0.f, 0.f};
      accu[a][b] = (f32x4){0.f, 0.f, 0.f, 0.f};
    }

  stage(0, 0);
  __syncthreads();
  for (int kt = 0; kt < nk; ++kt) {
    int cur = kt & 1;
    if (kt + 1 < nk) stage(cur ^ 1, kt + 1);
    short8 af[4], bg[NF], bu[NF];
#pragma unroll
    for (int mf = 0; mf < 4; ++mf)
      af[mf] = *(const short8*)&As[cur][swz64((w >> 1) * 64 + mf * 16 + (l & 15), (l >> 4) * 8)];
#pragma unroll
    for (int nf = 0; nf < NF; ++nf) {
      bg[nf] = *(const short8*)&Bg[cur][swz64((w & 1) * WN + nf * 16 + (l & 15), (l >> 4) * 8)];
      bu[nf] = *(const short8*)&Bu[cur][swz64((w & 1) * WN + nf * 16 + (l & 15), (l >> 4) * 8)];
    }
#pragma unroll
    for (int mf = 0; mf < 4; ++mf)
#pragma unroll
      for (int nf = 0; nf < NF; ++nf) {
        accg[mf][nf] = __builtin_amdgcn_mfma_f32_16x16x32_bf16(af[mf], bg[nf], accg[mf][nf], 0, 0, 0);
        accu[mf][nf] = __builtin_amdgcn_mfma_f32_16x16x32_bf16(af[mf], bu[nf], accu[mf][nf], 0, 0, 0);
      }
    __syncthreads();
  }

#pragma unroll
  for (int mf = 0; mf < 4; ++mf)
#pragma unroll
    for (int nf = 0; nf < NF; ++nf)
#pragma unroll
      for (int rr = 0; rr < 4; ++rr) {
        int row = m0 + (w >> 1) * 64 + mf * 16 + (l >> 4) * 4 + rr;
        int col = n0 + (w & 1) * WN + nf * 16 + (l & 15);
        float g = accg[mf][nf][rr], u = accu[mf][nf][rr];
        float s = g / (1.f + __expf(-g));  // silu
        out[(size_t)row * N + col] = f2bf(s * u);
      }
}

// ---------------------------------------------------------------- flash attention
__global__ __launch_bounds__(256) void attn_kernel(const bf16* __restrict__ qkv,
                                                   bf16* __restrict__ y) {
  const int bid = blockIdx.x;
  const int qb = bid & 7, hh = (bid >> 3) & 7, b = bid >> 6;
  const int tid = threadIdx.x, w = tid >> 6, l = tid & 63;
  __shared__ __align__(16) bf16 Qs[64 * 64];
  __shared__ __align__(16) bf16 Ks[64 * 64];
  __shared__ __align__(16) bf16 Vt[48 * 64];
  __shared__ __align__(16) bf16 Ps[64 * 64];
  const size_t bbase = (size_t)b * 512 * 864;

  for (int idx = tid; idx < 64 * 64; idx += 256) {
    ((unsigned short*)Qs)[idx] = 0;
    ((unsigned short*)Ks)[idx] = 0;
  }
  for (int idx = tid; idx < 48 * 64; idx += 256) ((unsigned short*)Vt)[idx] = 0;

  const bf16* qp = qkv + bbase + (size_t)(qb * 64) * 864 + hh * 36;
  for (int idx = tid; idx < 64 * 36; idx += 256) {
    int row = idx / 36, c = idx - row * 36;
    Qs[swz128(row, c)] = qp[(size_t)row * 864 + c];
  }
  __syncthreads();

  f32x4 oacc[3];
#pragma unroll
  for (int f = 0; f < 3; ++f) oacc[f] = (f32x4){0.f, 0.f, 0.f, 0.f};
  float mprev[4] = {-1e30f, -1e30f, -1e30f, -1e30f};
  float lsum[4] = {0.f, 0.f, 0.f, 0.f};
  const int qrow_base = qb * 64 + w * 16;

  for (int kt = 0; kt <= qb; ++kt) {
    const bf16* kp = qkv + bbase + (size_t)(kt * 64) * 864 + 288 + hh * 36;
    const bf16* vp = qkv + bbase + (size_t)(kt * 64) * 864 + 576 + hh * 36;
    for (int idx = tid; idx < 64 * 36; idx += 256) {
      int row = idx / 36, c = idx - row * 36;
      Ks[swz128(row, c)] = kp[(size_t)row * 864 + c];
      Vt[swz128(c, row)] = vp[(size_t)row * 864 + c];
    }
    __syncthreads();

    f32x4 sacc[4];
#pragma unroll
    for (int n = 0; n < 4; ++n) sacc[n] = (f32x4){0.f, 0.f, 0.f, 0.f};
#pragma unroll
    for (int s = 0; s < 2; ++s) {
      short8 aq = *(const short8*)&Qs[swz128(w * 16 + (l & 15), s * 32 + (l >> 4) * 8)];
#pragma unroll
      for (int n = 0; n < 4; ++n) {
        short8 bk = *(const short8*)&Ks[swz128(n * 16 + (l & 15), s * 32 + (l >> 4) * 8)];
        sacc[n] = __builtin_amdgcn_mfma_f32_16x16x32_bf16(aq, bk, sacc[n], 0, 0, 0);
      }
    }

    const bool diag = (kt == qb);
    float mt[4];
#pragma unroll
    for (int rr = 0; rr < 4; ++rr) {
      int qg = qrow_base + (l >> 4) * 4 + rr;
      float mx = -1e30f;
#pragma unroll
      for (int n = 0; n < 4; ++n) {
        float sv = sacc[n][rr] * (1.f / 6.f);
        if (diag) {
          int kg = kt * 64 + n * 16 + (l & 15);
          if (kg > qg) sv = -1e30f;
        }
        sacc[n][rr] = sv;
        mx = fmaxf(mx, sv);
      }
      mt[rr] = mx;
    }
#pragma unroll
    for (int off = 1; off < 16; off <<= 1)
#pragma unroll
      for (int rr = 0; rr < 4; ++rr) mt[rr] = fmaxf(mt[rr], __shfl_xor(mt[rr], off));

    float alpha[4], rs[4];
#pragma unroll
    for (int rr = 0; rr < 4; ++rr) {
      float mn = fmaxf(mprev[rr], mt[rr]);
      alpha[rr] = exp2f((mprev[rr] - mn) * LOG2E);
      mprev[rr] = mn;
      float ps = 0.f;
#pragma unroll
      for (int n = 0; n < 4; ++n) {
        float p = exp2f((sacc[n][rr] - mn) * LOG2E);
        sacc[n][rr] = p;
        ps += p;
      }
      rs[rr] = ps;
    }
#pragma unroll
    for (int off = 1; off < 16; off <<= 1)
#pragma unroll
      for (int rr = 0; rr < 4; ++rr) rs[rr] += __shfl_xor(rs[rr], off);
#pragma unroll
    for (int rr = 0; rr < 4; ++rr) lsum[rr] = lsum[rr] * alpha[rr] + rs[rr];
#pragma unroll
    for (int f = 0; f < 3; ++f)
#pragma unroll
      for (int rr = 0; rr < 4; ++rr) oacc[f][rr] *= alpha[rr];

#pragma unroll
    for (int n = 0; n < 4; ++n)
#pragma unroll
      for (int rr = 0; rr < 4; ++rr)
        Ps[swz128(w * 16 + (l >> 4) * 4 + rr, n * 16 + (l & 15))] = f2bf(sacc[n][rr]);
    __syncthreads();

#pragma unroll
    for (int s = 0; s < 2; ++s) {
      short8 ap = *(const short8*)&Ps[swz128(w * 16 + (l & 15), s * 32 + (l >> 4) * 8)];
#pragma unroll
      for (int f = 0; f < 3; ++f) {
        short8 bv = *(const short8*)&Vt[swz128(f * 16 + (l & 15), s * 32 + (l >> 4) * 8)];
        oacc[f] = __builtin_amdgcn_mfma_f32_16x16x32_bf16(ap, bv, oacc[f], 0, 0, 0);
      }
    }
    __syncthreads();
  }

#pragma unroll
  for (int rr = 0; rr < 4; ++rr) {
    float inv = 1.f / lsum[rr];
    int row = b * 512 + qb * 64 + w * 16 + (l >> 4) * 4 + rr;
    bf16* yr = y + (size_t)row * 288 + hh * 36;
#pragma unroll
    for (int f = 0; f < 3; ++f) {
      int col = f * 16 + (l & 15);
      if (col < 36) yr[col] = f2bf(oacc[f][rr] * inv);
    }
  }
}

// ---------------------------------------------------------------- launcher
extern "C" void kernel_launch(void* const* d_in, const int* in_sizes, int n_in,
                              void* d_out, int out_size, void* d_ws, size_t ws_size,
                              hipStream_t stream) {
  (void)in_sizes; (void)n_in; (void)out_size; (void)ws_size;
  const int* x = (const int*)d_in[0];
  const float* emb = (const float*)d_in[1];
  const float* pos = (const float*)d_in[2];
  const float* aqkv = (const float*)d_in[3];
  const float* aout = (const float*)d_in[4];
  const float* anorm = (const float*)d_in[5];
  const float* rin = (const float*)d_in[6];
  const float* rout = (const float*)d_in[7];
  const float* rnorm = (const float*)d_in[8];
  const float* fgate = (const float*)d_in[9];
  const float* fup = (const float*)d_in[10];
  const float* fdown = (const float*)d_in[11];
  const float* fnorm = (const float*)d_in[12];
  const float* finalnorm = (const float*)d_in[13];

  char* ws = (char*)d_ws;
  size_t off = 0;
  auto alloc = [&](size_t bytes) -> char* {
    char* p = ws + off;
    off += (bytes + 255) & ~(size_t)255;
    return p;
  };
  bf16* wqkv = (bf16*)alloc(4ull * 864 * 288 * 2);
  bf16* wao = (bf16*)alloc(4ull * 288 * 288 * 2);
  bf16* wrin = (bf16*)alloc(10ull * 864 * 288 * 2);
  bf16* wrout = (bf16*)alloc(10ull * 288 * 288 * 2);
  bf16* wg = (bf16*)alloc(14ull * 864 * 288 * 2);
  bf16* wu = (bf16*)alloc(14ull * 864 * 288 * 2);
  bf16* wd = (bf16*)alloc(14ull * 288 * 864 * 2);
  bf16* wemb = (bf16*)alloc(4096ull * 288 * 2);
  float* hbuf = (float*)alloc(16384ull * 288 * 4);
  bf16* xn = (bf16*)alloc(16384ull * 288 * 2);
  bf16* gvf = (bf16*)alloc(16384ull * 864 * 2);
  bf16* ybuf = (bf16*)alloc(16384ull * 288 * 2);
  float* Ap = (float*)alloc(16ull * 9216 * 4);
  float* Bp = (float*)alloc(16ull * 9216 * 4);

  auto cvt = [&](const float* src, bf16* dst, size_t n) {
    int n4 = (int)(n / 4);
    cvt_kernel<<<(n4 + 255) / 256, 256, 0, stream>>>(src, dst, n4);
  };
  cvt(aqkv, wqkv, 4ull * 864 * 288);
  cvt(aout, wao, 4ull * 288 * 288);
  cvt(rin, wrin, 10ull * 864 * 288);
  cvt(rout, wrout, 10ull * 288 * 288);
  cvt(fgate, wg, 14ull * 864 * 288);
  cvt(fup, wu, 14ull * 864 * 288);
  cvt(fdown, wd, 14ull * 288 * 864);
  cvt(emb, wemb, 4096ull * 288);

  // per-layer pre-norm scale pointers (lnorm[i] normalizes input of layer i)
  const float* lnorm[15];
  {
    int a2 = 0, r2 = 0;
    for (int j = 0; j < 14; ++j) {
      if ((j + 1) % 3 == 0) lnorm[j] = anorm + (a2++) * 288;
      else lnorm[j] = rnorm + (r2++) * 288;
    }
    lnorm[14] = finalnorm;
  }

  embed_norm_kernel<<<4096, 256, 0, stream>>>(x, emb, pos, lnorm[0], hbuf, xn);

  int ai = 0, ri = 0;
  for (int i = 0; i < 14; ++i) {
    const bool isattn = ((i + 1) % 3 == 0);
    if (isattn) {
      gemm_kernel<96, EPI_BF16><<<dim3(128, 9), 256, 0, stream>>>(
          xn, wqkv + (size_t)ai * 864 * 288, gvf, 864, 288);
      attn_kernel<<<2048, 256, 0, stream>>>(gvf, ybuf);
      gemm_row_kernel<<<256, 256, 0, stream>>>(
          ybuf, wao + (size_t)ai * 288 * 288, hbuf, xn, fnorm + i * 288, 288);
      ++ai;
    } else {
      gemm_kernel<96, EPI_GVF><<<dim3(128, 9), 256, 0, stream>>>(
          xn, wrin + (size_t)ri * 864 * 288, gvf, 864, 288);
      scanA_kernel<<<dim3(72, 16), 64, 0, stream>>>(gvf, Ap, Bp);
      scanC_kernel<<<dim3(72, 16), 64, 0, stream>>>(gvf, Ap, Bp, ybuf);
      gemm_row_kernel<<<256, 256, 0, stream>>>(
          ybuf, wrout + (size_t)ri * 288 * 288, hbuf, xn, fnorm + i * 288, 288);
      ++ri;
    }
    gateup_kernel<<<dim3(128, 9), 256, 0, stream>>>(
        xn, wg + (size_t)i * 864 * 288, wu + (size_t)i * 864 * 288, gvf, 864, 288);
    gemm_row_kernel<<<256, 256, 0, stream>>>(
        gvf, wd + (size_t)i * 288 * 864, hbuf, xn, lnorm[i + 1], 864);
  }
  gemm_kernel<128, EPI_F32><<<dim3(128, 32), 256, 0, stream>>>(
      xn, wemb, d_out, 4096, 288);
}

// Round 3
// 2431.698 us; speedup vs baseline: 1.2914x; 1.0882x over previous
//
#include <hip/hip_runtime.h>
#include <hip/hip_bf16.h>
#include <math.h>
#include <stdint.h>

using bf16 = __hip_bfloat16;
typedef __attribute__((ext_vector_type(8))) short short8;
typedef __attribute__((ext_vector_type(4))) float f32x4;

#define LOG2E 1.44269504088896340736f

enum { EPI_BF16 = 0, EPI_F32 = 3 };

__device__ __forceinline__ float bf2f(bf16 v) { return __bfloat162float(v); }
__device__ __forceinline__ bf16 f2bf(float v) { return __float2bfloat16(v); }
__device__ __forceinline__ unsigned short f2bfraw(float f) {
  bf16 h = __float2bfloat16(f);
  unsigned short u;
  __builtin_memcpy(&u, &h, 2);
  return u;
}
__device__ __forceinline__ float braw2f(unsigned short u) {
  unsigned x = (unsigned)u << 16;
  float f;
  __builtin_memcpy(&f, &x, 4);
  return f;
}

// LDS swizzle for 32-col (64B-row) bf16 tiles: chunk ^= (row>>1)&3.
__device__ __forceinline__ int swz64(int row, int col) {
  return row * 32 + ((((col >> 3) ^ ((row >> 1) & 3)) << 3) | (col & 7));
}
__device__ __forceinline__ int swz128(int row, int col) {
  return row * 64 + ((((col >> 3) ^ (row & 7)) << 3) | (col & 7));
}

// global -> LDS direct (width 16). dst wave-uniform; lane l fills dst+16*l.
__device__ __forceinline__ void gload16(const bf16* src, bf16* dst) {
  __builtin_amdgcn_global_load_lds(
      (const __attribute__((address_space(1))) void*)src,
      (__attribute__((address_space(3))) void*)dst, 16, 0, 0);
}

// ---------------------------------------------------------------- convert (all weights, 1 kernel)
struct CvtPtrs {
  const float* s[8];
  bf16* d[8];
};
__global__ __launch_bounds__(256) void cvt_all_kernel(CvtPtrs p) {
  int i = blockIdx.x * 256 + threadIdx.x;  // float4 index, 4068864 total
  const float* src;
  bf16* dst;
  int li = i;
  if (i < 248832)       { src = p.s[0]; dst = p.d[0]; }
  else if (i < 331776)  { src = p.s[1]; dst = p.d[1]; li = i - 248832; }
  else if (i < 953856)  { src = p.s[2]; dst = p.d[2]; li = i - 331776; }
  else if (i < 1161216) { src = p.s[3]; dst = p.d[3]; li = i - 953856; }
  else if (i < 2032128) { src = p.s[4]; dst = p.d[4]; li = i - 1161216; }
  else if (i < 2903040) { src = p.s[5]; dst = p.d[5]; li = i - 2032128; }
  else if (i < 3773952) { src = p.s[6]; dst = p.d[6]; li = i - 2903040; }
  else                  { src = p.s[7]; dst = p.d[7]; li = i - 3773952; }
  const float4 v = ((const float4*)src)[li];
  uint2 pk;
  pk.x = (unsigned)f2bfraw(v.x) | ((unsigned)f2bfraw(v.y) << 16);
  pk.y = (unsigned)f2bfraw(v.z) | ((unsigned)f2bfraw(v.w) << 16);
  ((uint2*)dst)[li] = pk;
}

// ---------------------------------------------------------------- embed + norm
__global__ __launch_bounds__(256) void embed_norm_kernel(const int* __restrict__ x,
                                                         const float* __restrict__ emb,
                                                         const float* __restrict__ pos,
                                                         const float* __restrict__ sc,
                                                         float* __restrict__ hbuf,
                                                         bf16* __restrict__ xn) {
  int row = blockIdx.x * 4 + (threadIdx.x >> 6);
  int lane = threadIdx.x & 63;
  int tok = x[row];
  const float* e = emb + (size_t)tok * 288;
  const float* p = pos + (size_t)(row & 511) * 288;
  float v[5];
  float ss = 0.f;
#pragma unroll
  for (int j = 0; j < 4; ++j) {
    v[j] = e[j * 64 + lane] + p[j * 64 + lane];
    ss += v[j] * v[j];
  }
  v[4] = (lane < 32) ? (e[256 + lane] + p[256 + lane]) : 0.f;
  ss += v[4] * v[4];
#pragma unroll
  for (int off = 32; off > 0; off >>= 1) ss += __shfl_xor(ss, off);
  float inv = 1.f / (sqrtf(ss * (1.f / 288.f)) + 1e-6f);
  float* hr = hbuf + (size_t)row * 288;
  bf16* xr = xn + (size_t)row * 288;
#pragma unroll
  for (int j = 0; j < 4; ++j) {
    hr[j * 64 + lane] = v[j];
    xr[j * 64 + lane] = f2bf(v[j] * inv * sc[j * 64 + lane]);
  }
  if (lane < 32) {
    hr[256 + lane] = v[4];
    xr[256 + lane] = f2bf(v[4] * inv * sc[256 + lane]);
  }
}

// ---------------------------------------------------------------- scan pass C
// fold chunk summaries (Ap/Bp from the fused in-proj epilogue), roll 32 t.
__global__ __launch_bounds__(64) void scanC_kernel(const bf16* __restrict__ gvf,
                                                   const float* __restrict__ Ap,
                                                   const float* __restrict__ Bp,
                                                   bf16* __restrict__ y) {
  int g = blockIdx.x * 64 + threadIdx.x;
  int c = blockIdx.y;
  int b = g / 144, dp = g - b * 144;
  int half = b * 144 + dp;
  float h0 = 0.f, h1 = 0.f;
  for (int cc = 0; cc < c; ++cc) {
    float2 a = ((const float2*)(Ap + (size_t)cc * 9216))[half];
    float2 bb = ((const float2*)(Bp + (size_t)cc * 9216))[half];
    h0 = bb.x + a.x * h0;
    h1 = bb.y + a.y * h1;
  }
  const bf16* base = gvf + (size_t)b * 512 * 864 + (size_t)c * 32 * 864 + dp * 2;
  bf16* yb = y + (size_t)b * 512 * 288 + (size_t)c * 32 * 288 + dp * 2;
#pragma unroll 4
  for (int t = 0; t < 32; ++t) {
    unsigned gg = *(const unsigned*)(base + (size_t)t * 864);
    unsigned vv = *(const unsigned*)(base + (size_t)t * 864 + 288);
    unsigned ff = *(const unsigned*)(base + (size_t)t * 864 + 576);
    float g0 = braw2f((unsigned short)gg), g1 = braw2f((unsigned short)(gg >> 16));
    float v0 = braw2f((unsigned short)vv), v1 = braw2f((unsigned short)(vv >> 16));
    float f0 = braw2f((unsigned short)ff), f1 = braw2f((unsigned short)(ff >> 16));
    h0 = f0 * h0 + (1.f - f0) * v0;
    h1 = f1 * h1 + (1.f - f1) * v1;
    unsigned o = (unsigned)f2bfraw(g0 * h0) | ((unsigned)f2bfraw(g1 * h1) << 16);
    *(unsigned*)(yb + (size_t)t * 288) = o;
  }
}

// ---------------------------------------------------------------- GEMM (tiled)
// out[M,N] = A[M,K] @ W[N,K]^T. 128 x BN tile, BK=32, 4 waves (2x2).
template <int BN, int EPI>
__global__ __launch_bounds__(256) void gemm_kernel(const bf16* __restrict__ A,
                                                   const bf16* __restrict__ W,
                                                   void* __restrict__ outv,
                                                   int N, int K) {
  constexpr int WN = BN / 2;
  constexpr int NF = WN / 16;
  constexpr int TC = 8 + BN / 16;
  __shared__ __align__(16) bf16 As[2][128 * 32];
  __shared__ __align__(16) bf16 Bs[2][BN * 32];
  const int tid = threadIdx.x;
  const int w = tid >> 6, l = tid & 63;
  const int m0 = blockIdx.x * 128;
  const int n0 = blockIdx.y * BN;
  const int nk = K >> 5;
  const int lrow = l >> 2, lslot = l & 3;

  auto stage = [&](int buf, int kt) {
    for (int wc = w; wc < TC; wc += 4) {
      const bf16* src;
      bf16* dst;
      int row;
      if (wc < 8) {
        row = wc * 16 + lrow;
        src = A + (size_t)(m0 + row) * K;
        dst = &As[buf][wc * 512];
      } else {
        row = (wc - 8) * 16 + lrow;
        src = W + (size_t)(n0 + row) * K;
        dst = &Bs[buf][(wc - 8) * 512];
      }
      int slot = lslot ^ ((row >> 1) & 3);
      gload16(src + kt * 32 + slot * 8, dst);
    }
  };

  f32x4 acc[4][NF];
#pragma unroll
  for (int a = 0; a < 4; ++a)
#pragma unroll
    for (int b = 0; b < NF; ++b) acc[a][b] = (f32x4){0.f, 0.f, 0.f, 0.f};

  stage(0, 0);
  __syncthreads();
  for (int kt = 0; kt < nk; ++kt) {
    int cur = kt & 1;
    if (kt + 1 < nk) stage(cur ^ 1, kt + 1);
    short8 af[4], bfr[NF];
#pragma unroll
    for (int mf = 0; mf < 4; ++mf)
      af[mf] = *(const short8*)&As[cur][swz64((w >> 1) * 64 + mf * 16 + (l & 15), (l >> 4) * 8)];
#pragma unroll
    for (int nf = 0; nf < NF; ++nf)
      bfr[nf] = *(const short8*)&Bs[cur][swz64((w & 1) * WN + nf * 16 + (l & 15), (l >> 4) * 8)];
#pragma unroll
    for (int mf = 0; mf < 4; ++mf)
#pragma unroll
      for (int nf = 0; nf < NF; ++nf)
        acc[mf][nf] = __builtin_amdgcn_mfma_f32_16x16x32_bf16(af[mf], bfr[nf], acc[mf][nf], 0, 0, 0);
    __syncthreads();
  }

#pragma unroll
  for (int mf = 0; mf < 4; ++mf) {
#pragma unroll
    for (int nf = 0; nf < NF; ++nf) {
#pragma unroll
      for (int rr = 0; rr < 4; ++rr) {
        int row = m0 + (w >> 1) * 64 + mf * 16 + (l >> 4) * 4 + rr;
        int col = n0 + (w & 1) * WN + nf * 16 + (l & 15);
        float v = acc[mf][nf][rr];
        size_t o = (size_t)row * N + col;
        if (EPI == EPI_BF16) {
          ((bf16*)outv)[o] = f2bf(v);
        } else {
          ((float*)outv)[o] = v;
        }
      }
    }
  }
}

// ---------------------------------------------------------------- rec in-proj GEMM + fused scanA
// N-tile j covers channels [32j,32j+32): col layout per tile is
// [g(0-15), v(0-15), f(0-15), g(16-31), v(16-31), f(16-31)] so each 16-lane
// group holds g,v,f of the SAME channel. Epilogue writes gvf (global layout
// unchanged) + per-chunk affine scan summaries (A,B) -> Ap/Bp.
__global__ __launch_bounds__(256) void gemm_gvf_scan_kernel(const bf16* __restrict__ A,
                                                            const bf16* __restrict__ W,
                                                            bf16* __restrict__ gvf,
                                                            float* __restrict__ Ap,
                                                            float* __restrict__ Bp,
                                                            int K) {
  __shared__ __align__(16) bf16 As[2][128 * 32];
  __shared__ __align__(16) bf16 Bs[2][96 * 32];
  const int tid = threadIdx.x;
  const int w = tid >> 6, l = tid & 63;
  const int m0 = blockIdx.x * 128;
  const int ch0 = blockIdx.y * 32;
  const int nk = K >> 5;
  const int lrow = l >> 2, lslot = l & 3;

  auto stage = [&](int buf, int kt) {
    for (int wc = w; wc < 14; wc += 4) {
      const bf16* src;
      bf16* dst;
      int ldsrow;
      if (wc < 8) {
        ldsrow = wc * 16 + lrow;
        src = A + (size_t)(m0 + ldsrow) * K;
        dst = &As[buf][wc * 512];
      } else {
        int r96 = (wc - 8) * 16 + lrow;
        ldsrow = r96;
        int gr = r96 >> 4;                       // 0..5
        int sec = (gr >= 3) ? (gr - 3) : gr;     // 0=g,1=v,2=f
        int offc = (gr >= 3) ? 16 : 0;
        src = W + (size_t)(sec * 288 + ch0 + offc + (r96 & 15)) * K;
        dst = &Bs[buf][(wc - 8) * 512];
      }
      int slot = lslot ^ ((ldsrow >> 1) & 3);
      gload16(src + kt * 32 + slot * 8, dst);
    }
  };

  f32x4 acc[4][3];
#pragma unroll
  for (int a = 0; a < 4; ++a)
#pragma unroll
    for (int b = 0; b < 3; ++b) acc[a][b] = (f32x4){0.f, 0.f, 0.f, 0.f};

  stage(0, 0);
  __syncthreads();
  for (int kt = 0; kt < nk; ++kt) {
    int cur = kt & 1;
    if (kt + 1 < nk) stage(cur ^ 1, kt + 1);
    short8 af[4], bfr[3];
#pragma unroll
    for (int mf = 0; mf < 4; ++mf)
      af[mf] = *(const short8*)&As[cur][swz64((w >> 1) * 64 + mf * 16 + (l & 15), (l >> 4) * 8)];
#pragma unroll
    for (int nf = 0; nf < 3; ++nf)
      bfr[nf] = *(const short8*)&Bs[cur][swz64((w & 1) * 48 + nf * 16 + (l & 15), (l >> 4) * 8)];
#pragma unroll
    for (int mf = 0; mf < 4; ++mf)
#pragma unroll
      for (int nf = 0; nf < 3; ++nf)
        acc[mf][nf] = __builtin_amdgcn_mfma_f32_16x16x32_bf16(af[mf], bfr[nf], acc[mf][nf], 0, 0, 0);
    __syncthreads();
  }

  // epilogue: sigmoid + gvf write + in-register chunk scan summary
  const int chg = ch0 + (w & 1) * 16 + (l & 15);
  const int bb = m0 >> 9;
  const int lq = l >> 4;  // t offset 4*lq within a 16-row fragment
  float Asub[4], Bsub[4];
#pragma unroll
  for (int mf = 0; mf < 4; ++mf) {
    float Aa = 1.f, Bb = 0.f;
#pragma unroll
    for (int rr = 0; rr < 4; ++rr) {
      int row = m0 + (w >> 1) * 64 + mf * 16 + lq * 4 + rr;
      float gv = acc[mf][0][rr];
      float vv = acc[mf][1][rr];
      float fv = acc[mf][2][rr];
      float gs = 1.f / (1.f + __expf(-gv));
      float fs = 1.f / (1.f + __expf(-(fv - 1.f)));
      bf16 gb = f2bf(gs), vb = f2bf(vv), fb = f2bf(fs);
      bf16* gp = gvf + (size_t)row * 864;
      gp[chg] = gb;
      gp[288 + chg] = vb;
      gp[576 + chg] = fb;
      float fr = bf2f(fb), vr = bf2f(vb);  // match scanC's bf16-rounded math
      Aa = fr * Aa;
      Bb = fr * Bb + (1.f - fr) * vr;
    }
    Asub[mf] = Aa;
    Bsub[mf] = Bb;
  }
  // butterfly affine compose across lane bit4 (t+4) and bit5 (t+8)
#pragma unroll
  for (int mf = 0; mf < 4; ++mf) {
#pragma unroll
    for (int bit = 16; bit <= 32; bit <<= 1) {
      float Ao = __shfl_xor(Asub[mf], bit);
      float Bo = __shfl_xor(Bsub[mf], bit);
      if (l & bit) {  // I am the later t-half: full = me o partner
        Bsub[mf] = Asub[mf] * Bo + Bsub[mf];
        Asub[mf] = Asub[mf] * Ao;
      } else {        // partner later: full = partner o me
        Bsub[mf] = Ao * Bsub[mf] + Bo;
        Asub[mf] = Ao * Asub[mf];
      }
    }
  }
  if (lq == 0) {
    float Ac0 = Asub[1] * Asub[0], Bc0 = Asub[1] * Bsub[0] + Bsub[1];
    float Ac1 = Asub[3] * Asub[2], Bc1 = Asub[3] * Bsub[2] + Bsub[3];
    int cbase = ((m0 & 511) >> 5) + (w >> 1) * 2;
    size_t ix = (size_t)bb * 288 + chg;
    Ap[(size_t)cbase * 9216 + ix] = Ac0;
    Bp[(size_t)cbase * 9216 + ix] = Bc0;
    Ap[(size_t)(cbase + 1) * 9216 + ix] = Ac1;
    Bp[(size_t)(cbase + 1) * 9216 + ix] = Bc1;
  }
}

// ---------------------------------------------------------------- GEMM full-row (8 waves)
// out/down-proj: 64 x 288 tile; 8 waves (4M x 2N). Epilogue: residual add +
// rmsnorm; writes hbuf (fp32) and xn = norm(h)*scale (bf16).
__global__ __launch_bounds__(512) void gemm_row_kernel(const bf16* __restrict__ A,
                                                       const bf16* __restrict__ W,
                                                       float* __restrict__ hbuf,
                                                       bf16* __restrict__ xn,
                                                       const float* __restrict__ scale,
                                                       int K) {
  __shared__ __align__(16) bf16 As[2][64 * 32];
  __shared__ __align__(16) bf16 Bs[2][288 * 32];
  __shared__ float ssx[2][64];
  const int tid = threadIdx.x;
  const int w = tid >> 6, l = tid & 63;
  const int wm = w >> 1, wn = w & 1;
  const int m0 = blockIdx.x * 64;
  const int nk = K >> 5;
  const int lrow = l >> 2, lslot = l & 3;

  auto stage = [&](int buf, int kt) {
    for (int wc = w; wc < 22; wc += 8) {
      const bf16* src;
      bf16* dst;
      int row;
      if (wc < 4) {
        row = wc * 16 + lrow;
        src = A + (size_t)(m0 + row) * K;
        dst = &As[buf][wc * 512];
      } else {
        row = (wc - 4) * 16 + lrow;
        src = W + (size_t)row * K;
        dst = &Bs[buf][(wc - 4) * 512];
      }
      int slot = lslot ^ ((row >> 1) & 3);
      gload16(src + kt * 32 + slot * 8, dst);
    }
  };

  f32x4 acc[9];
#pragma unroll
  for (int b = 0; b < 9; ++b) acc[b] = (f32x4){0.f, 0.f, 0.f, 0.f};

  stage(0, 0);
  __syncthreads();
  for (int kt = 0; kt < nk; ++kt) {
    int cur = kt & 1;
    if (kt + 1 < nk) stage(cur ^ 1, kt + 1);
    short8 af = *(const short8*)&As[cur][swz64(wm * 16 + (l & 15), (l >> 4) * 8)];
#pragma unroll
    for (int nf = 0; nf < 9; ++nf) {
      short8 bv = *(const short8*)&Bs[cur][swz64(wn * 144 + nf * 16 + (l & 15), (l >> 4) * 8)];
      acc[nf] = __builtin_amdgcn_mfma_f32_16x16x32_bf16(af, bv, acc[nf], 0, 0, 0);
    }
    __syncthreads();
  }

  // epilogue: v = acc + residual; row sum-sq; hbuf = v; xn = v*invnorm*scale
  float ss4[4] = {0.f, 0.f, 0.f, 0.f};
#pragma unroll
  for (int nf = 0; nf < 9; ++nf)
#pragma unroll
    for (int rr = 0; rr < 4; ++rr) {
      int rowl = wm * 16 + (l >> 4) * 4 + rr;
      int col = wn * 144 + nf * 16 + (l & 15);
      size_t o = (size_t)(m0 + rowl) * 288 + col;
      float v = acc[nf][rr] + hbuf[o];
      hbuf[o] = v;
      acc[nf][rr] = v;
      ss4[rr] += v * v;
    }
#pragma unroll
  for (int off = 1; off < 16; off <<= 1)
#pragma unroll
    for (int rr = 0; rr < 4; ++rr) ss4[rr] += __shfl_xor(ss4[rr], off);
  if ((l & 15) == 0) {
#pragma unroll
    for (int rr = 0; rr < 4; ++rr) ssx[wn][wm * 16 + (l >> 4) * 4 + rr] = ss4[rr];
  }
  __syncthreads();
  float inv[4];
#pragma unroll
  for (int rr = 0; rr < 4; ++rr) {
    int rowl = wm * 16 + (l >> 4) * 4 + rr;
    float tot = ssx[0][rowl] + ssx[1][rowl];
    inv[rr] = 1.f / (sqrtf(tot * (1.f / 288.f)) + 1e-6f);
  }
#pragma unroll
  for (int nf = 0; nf < 9; ++nf) {
    int col = wn * 144 + nf * 16 + (l & 15);
    float sc = scale[col];
#pragma unroll
    for (int rr = 0; rr < 4; ++rr) {
      int rowl = wm * 16 + (l >> 4) * 4 + rr;
      size_t o = (size_t)(m0 + rowl) * 288 + col;
      xn[o] = f2bf(acc[nf][rr] * inv[rr] * sc);
    }
  }
}

// ---------------------------------------------------------------- gate+up fused
__global__ __launch_bounds__(256) void gateup_kernel(const bf16* __restrict__ A,
                                                     const bf16* __restrict__ Wg,
                                                     const bf16* __restrict__ Wu,
                                                     bf16* __restrict__ out, int N, int K) {
  constexpr int WN = 48, NF = 3;
  __shared__ __align__(16) bf16 As[2][128 * 32];
  __shared__ __align__(16) bf16 Bg[2][96 * 32];
  __shared__ __align__(16) bf16 Bu[2][96 * 32];
  const int tid = threadIdx.x;
  const int w = tid >> 6, l = tid & 63;
  const int m0 = blockIdx.x * 128;
  const int n0 = blockIdx.y * 96;
  const int nk = K >> 5;
  const int lrow = l >> 2, lslot = l & 3;

  auto stage = [&](int buf, int kt) {
    for (int wc = w; wc < 20; wc += 4) {
      const bf16* src;
      bf16* dst;
      int row;
      if (wc < 8) {
        row = wc * 16 + lrow;
        src = A + (size_t)(m0 + row) * K;
        dst = &As[buf][wc * 512];
      } else if (wc < 14) {
        row = (wc - 8) * 16 + lrow;
        src = Wg + (size_t)(n0 + row) * K;
        dst = &Bg[buf][(wc - 8) * 512];
      } else {
        row = (wc - 14) * 16 + lrow;
        src = Wu + (size_t)(n0 + row) * K;
        dst = &Bu[buf][(wc - 14) * 512];
      }
      int slot = lslot ^ ((row >> 1) & 3);
      gload16(src + kt * 32 + slot * 8, dst);
    }
  };

  f32x4 accg[4][NF], accu[4][NF];
#pragma unroll
  for (int a = 0; a < 4; ++a)
#pragma unroll
    for (int b = 0; b < NF; ++b) {
      accg[a][b] = (f32x4){0.f, 0.f, 0.f, 0.f};
      accu[a][b] = (f32x4){0.f, 0.f, 0.f, 0.f};
    }

  stage(0, 0);
  __syncthreads();
  for (int kt = 0; kt < nk; ++kt) {
    int cur = kt & 1;
    if (kt + 1 < nk) stage(cur ^ 1, kt + 1);
    short8 af[4], bg[NF], bu[NF];
#pragma unroll
    for (int mf = 0; mf < 4; ++mf)
      af[mf] = *(const short8*)&As[cur][swz64((w >> 1) * 64 + mf * 16 + (l & 15), (l >> 4) * 8)];
#pragma unroll
    for (int nf = 0; nf < NF; ++nf) {
      bg[nf] = *(const short8*)&Bg[cur][swz64((w & 1) * WN + nf * 16 + (l & 15), (l >> 4) * 8)];
      bu[nf] = *(const short8*)&Bu[cur][swz64((w & 1) * WN + nf * 16 + (l & 15), (l >> 4) * 8)];
    }
#pragma unroll
    for (int mf = 0; mf < 4; ++mf)
#pragma unroll
      for (int nf = 0; nf < NF; ++nf) {
        accg[mf][nf] = __builtin_amdgcn_mfma_f32_16x16x32_bf16(af[mf], bg[nf], accg[mf][nf], 0, 0, 0);
        accu[mf][nf] = __builtin_amdgcn_mfma_f32_16x16x32_bf16(af[mf], bu[nf], accu[mf][nf], 0, 0, 0);
      }
    __syncthreads();
  }

#pragma unroll
  for (int mf = 0; mf < 4; ++mf)
#pragma unroll
    for (int nf = 0; nf < NF; ++nf)
#pragma unroll
      for (int rr = 0; rr < 4; ++rr) {
        int row = m0 + (w >> 1) * 64 + mf * 16 + (l >> 4) * 4 + rr;
        int col = n0 + (w & 1) * WN + nf * 16 + (l & 15);
        float g = accg[mf][nf][rr], u = accu[mf][nf][rr];
        float s = g / (1.f + __expf(-g));  // silu
        out[(size_t)row * N + col] = f2bf(s * u);
      }
}

// ---------------------------------------------------------------- flash attention
__global__ __launch_bounds__(256) void attn_kernel(const bf16* __restrict__ qkv,
                                                   bf16* __restrict__ y) {
  const int bid = blockIdx.x;
  const int qb = bid & 7, hh = (bid >> 3) & 7, b = bid >> 6;
  const int tid = threadIdx.x, w = tid >> 6, l = tid & 63;
  __shared__ __align__(16) bf16 Qs[64 * 64];
  __shared__ __align__(16) bf16 Ks[64 * 64];
  __shared__ __align__(16) bf16 Vt[48 * 64];
  __shared__ __align__(16) bf16 Ps[64 * 64];
  const size_t bbase = (size_t)b * 512 * 864;

  for (int idx = tid; idx < 64 * 64; idx += 256) {
    ((unsigned short*)Qs)[idx] = 0;
    ((unsigned short*)Ks)[idx] = 0;
  }
  for (int idx = tid; idx < 48 * 64; idx += 256) ((unsigned short*)Vt)[idx] = 0;

  const bf16* qp = qkv + bbase + (size_t)(qb * 64) * 864 + hh * 36;
  for (int idx = tid; idx < 64 * 36; idx += 256) {
    int row = idx / 36, c = idx - row * 36;
    Qs[swz128(row, c)] = qp[(size_t)row * 864 + c];
  }
  __syncthreads();

  f32x4 oacc[3];
#pragma unroll
  for (int f = 0; f < 3; ++f) oacc[f] = (f32x4){0.f, 0.f, 0.f, 0.f};
  float mprev[4] = {-1e30f, -1e30f, -1e30f, -1e30f};
  float lsum[4] = {0.f, 0.f, 0.f, 0.f};
  const int qrow_base = qb * 64 + w * 16;

  for (int kt = 0; kt <= qb; ++kt) {
    const bf16* kp = qkv + bbase + (size_t)(kt * 64) * 864 + 288 + hh * 36;
    const bf16* vp = qkv + bbase + (size_t)(kt * 64) * 864 + 576 + hh * 36;
    for (int idx = tid; idx < 64 * 36; idx += 256) {
      int row = idx / 36, c = idx - row * 36;
      Ks[swz128(row, c)] = kp[(size_t)row * 864 + c];
      Vt[swz128(c, row)] = vp[(size_t)row * 864 + c];
    }
    __syncthreads();

    f32x4 sacc[4];
#pragma unroll
    for (int n = 0; n < 4; ++n) sacc[n] = (f32x4){0.f, 0.f, 0.f, 0.f};
#pragma unroll
    for (int s = 0; s < 2; ++s) {
      short8 aq = *(const short8*)&Qs[swz128(w * 16 + (l & 15), s * 32 + (l >> 4) * 8)];
#pragma unroll
      for (int n = 0; n < 4; ++n) {
        short8 bk = *(const short8*)&Ks[swz128(n * 16 + (l & 15), s * 32 + (l >> 4) * 8)];
        sacc[n] = __builtin_amdgcn_mfma_f32_16x16x32_bf16(aq, bk, sacc[n], 0, 0, 0);
      }
    }

    const bool diag = (kt == qb);
    float mt[4];
#pragma unroll
    for (int rr = 0; rr < 4; ++rr) {
      int qg = qrow_base + (l >> 4) * 4 + rr;
      float mx = -1e30f;
#pragma unroll
      for (int n = 0; n < 4; ++n) {
        float sv = sacc[n][rr] * (1.f / 6.f);
        if (diag) {
          int kg = kt * 64 + n * 16 + (l & 15);
          if (kg > qg) sv = -1e30f;
        }
        sacc[n][rr] = sv;
        mx = fmaxf(mx, sv);
      }
      mt[rr] = mx;
    }
#pragma unroll
    for (int off = 1; off < 16; off <<= 1)
#pragma unroll
      for (int rr = 0; rr < 4; ++rr) mt[rr] = fmaxf(mt[rr], __shfl_xor(mt[rr], off));

    float alpha[4], rs[4];
#pragma unroll
    for (int rr = 0; rr < 4; ++rr) {
      float mn = fmaxf(mprev[rr], mt[rr]);
      alpha[rr] = exp2f((mprev[rr] - mn) * LOG2E);
      mprev[rr] = mn;
      float ps = 0.f;
#pragma unroll
      for (int n = 0; n < 4; ++n) {
        float p = exp2f((sacc[n][rr] - mn) * LOG2E);
        sacc[n][rr] = p;
        ps += p;
      }
      rs[rr] = ps;
    }
#pragma unroll
    for (int off = 1; off < 16; off <<= 1)
#pragma unroll
      for (int rr = 0; rr < 4; ++rr) rs[rr] += __shfl_xor(rs[rr], off);
#pragma unroll
    for (int rr = 0; rr < 4; ++rr) lsum[rr] = lsum[rr] * alpha[rr] + rs[rr];
#pragma unroll
    for (int f = 0; f < 3; ++f)
#pragma unroll
      for (int rr = 0; rr < 4; ++rr) oacc[f][rr] *= alpha[rr];

#pragma unroll
    for (int n = 0; n < 4; ++n)
#pragma unroll
      for (int rr = 0; rr < 4; ++rr)
        Ps[swz128(w * 16 + (l >> 4) * 4 + rr, n * 16 + (l & 15))] = f2bf(sacc[n][rr]);
    __syncthreads();

#pragma unroll
    for (int s = 0; s < 2; ++s) {
      short8 ap = *(const short8*)&Ps[swz128(w * 16 + (l & 15), s * 32 + (l >> 4) * 8)];
#pragma unroll
      for (int f = 0; f < 3; ++f) {
        short8 bv = *(const short8*)&Vt[swz128(f * 16 + (l & 15), s * 32 + (l >> 4) * 8)];
        oacc[f] = __builtin_amdgcn_mfma_f32_16x16x32_bf16(ap, bv, oacc[f], 0, 0, 0);
      }
    }
    __syncthreads();
  }

#pragma unroll
  for (int rr = 0; rr < 4; ++rr) {
    float inv = 1.f / lsum[rr];
    int row = b * 512 + qb * 64 + w * 16 + (l >> 4) * 4 + rr;
    bf16* yr = y + (size_t)row * 288 + hh * 36;
#pragma unroll
    for (int f = 0; f < 3; ++f) {
      int col = f * 16 + (l & 15);
      if (col < 36) yr[col] = f2bf(oacc[f][rr] * inv);
    }
  }
}

// ---------------------------------------------------------------- launcher
extern "C" void kernel_launch(void* const* d_in, const int* in_sizes, int n_in,
                              void* d_out, int out_size, void* d_ws, size_t ws_size,
                              hipStream_t stream) {
  (void)in_sizes; (void)n_in; (void)out_size; (void)ws_size;
  const int* x = (const int*)d_in[0];
  const float* emb = (const float*)d_in[1];
  const float* pos = (const float*)d_in[2];
  const float* aqkv = (const float*)d_in[3];
  const float* aout = (const float*)d_in[4];
  const float* anorm = (const float*)d_in[5];
  const float* rin = (const float*)d_in[6];
  const float* rout = (const float*)d_in[7];
  const float* rnorm = (const float*)d_in[8];
  const float* fgate = (const float*)d_in[9];
  const float* fup = (const float*)d_in[10];
  const float* fdown = (const float*)d_in[11];
  const float* fnorm = (const float*)d_in[12];
  const float* finalnorm = (const float*)d_in[13];

  char* ws = (char*)d_ws;
  size_t off = 0;
  auto alloc = [&](size_t bytes) -> char* {
    char* p = ws + off;
    off += (bytes + 255) & ~(size_t)255;
    return p;
  };
  bf16* wqkv = (bf16*)alloc(4ull * 864 * 288 * 2);
  bf16* wao = (bf16*)alloc(4ull * 288 * 288 * 2);
  bf16* wrin = (bf16*)alloc(10ull * 864 * 288 * 2);
  bf16* wrout = (bf16*)alloc(10ull * 288 * 288 * 2);
  bf16* wg = (bf16*)alloc(14ull * 864 * 288 * 2);
  bf16* wu = (bf16*)alloc(14ull * 864 * 288 * 2);
  bf16* wd = (bf16*)alloc(14ull * 288 * 864 * 2);
  bf16* wemb = (bf16*)alloc(4096ull * 288 * 2);
  float* hbuf = (float*)alloc(16384ull * 288 * 4);
  bf16* xn = (bf16*)alloc(16384ull * 288 * 2);
  bf16* gvf = (bf16*)alloc(16384ull * 864 * 2);
  bf16* ybuf = (bf16*)alloc(16384ull * 288 * 2);
  float* Ap = (float*)alloc(16ull * 9216 * 4);
  float* Bp = (float*)alloc(16ull * 9216 * 4);

  CvtPtrs cp;
  cp.s[0] = aqkv;  cp.d[0] = wqkv;
  cp.s[1] = aout;  cp.d[1] = wao;
  cp.s[2] = rin;   cp.d[2] = wrin;
  cp.s[3] = rout;  cp.d[3] = wrout;
  cp.s[4] = fgate; cp.d[4] = wg;
  cp.s[5] = fup;   cp.d[5] = wu;
  cp.s[6] = fdown; cp.d[6] = wd;
  cp.s[7] = emb;   cp.d[7] = wemb;
  cvt_all_kernel<<<15894, 256, 0, stream>>>(cp);

  // per-layer pre-norm scale pointers (lnorm[i] normalizes input of layer i)
  const float* lnorm[15];
  {
    int a2 = 0, r2 = 0;
    for (int j = 0; j < 14; ++j) {
      if ((j + 1) % 3 == 0) lnorm[j] = anorm + (a2++) * 288;
      else lnorm[j] = rnorm + (r2++) * 288;
    }
    lnorm[14] = finalnorm;
  }

  embed_norm_kernel<<<4096, 256, 0, stream>>>(x, emb, pos, lnorm[0], hbuf, xn);

  int ai = 0, ri = 0;
  for (int i = 0; i < 14; ++i) {
    const bool isattn = ((i + 1) % 3 == 0);
    if (isattn) {
      gemm_kernel<96, EPI_BF16><<<dim3(128, 9), 256, 0, stream>>>(
          xn, wqkv + (size_t)ai * 864 * 288, gvf, 864, 288);
      attn_kernel<<<2048, 256, 0, stream>>>(gvf, ybuf);
      gemm_row_kernel<<<256, 512, 0, stream>>>(
          ybuf, wao + (size_t)ai * 288 * 288, hbuf, xn, fnorm + i * 288, 288);
      ++ai;
    } else {
      gemm_gvf_scan_kernel<<<dim3(128, 9), 256, 0, stream>>>(
          xn, wrin + (size_t)ri * 864 * 288, gvf, Ap, Bp, 288);
      scanC_kernel<<<dim3(72, 16), 64, 0, stream>>>(gvf, Ap, Bp, ybuf);
      gemm_row_kernel<<<256, 512, 0, stream>>>(
          ybuf, wrout + (size_t)ri * 288 * 288, hbuf, xn, fnorm + i * 288, 288);
      ++ri;
    }
    gateup_kernel<<<dim3(128, 9), 256, 0, stream>>>(
        xn, wg + (size_t)i * 864 * 288, wu + (size_t)i * 864 * 288, gvf, 864, 288);
    gemm_row_kernel<<<256, 512, 0, stream>>>(
        gvf, wd + (size_t)i * 288 * 864, hbuf, xn, lnorm[i + 1], 864);
  }
  gemm_kernel<128, EPI_F32><<<dim3(128, 32), 256, 0, stream>>>(
      xn, wemb, d_out, 4096, 288);
}